// Round 1
// baseline (1024.826 us; speedup 1.0000x reference)
//
#include <hip/hip_runtime.h>
#include <math.h>

// ---------------------------------------------------------------------------
// SAGPool GNN forward: 3x [GCNConv -> SAGPool(top-k) -> readout] + MLP head.
// Problem constants (fixed by reference):
//   B=32 graphs x N=2048 nodes; E = 32*16384 edges; 128 feats; K = 1024/512/256
// Strategy:
//   - Build CSR (incoming edges per dst) ONCE per call -> all aggregations are
//     gathers (no float atomics on the 65536x128 feature scatter).
//   - deg/dinv/coef shared between main GCN and score GCN (same masks).
//   - top-k per graph: bitonic sort of 2048 masked scores in LDS, threshold +
//     index-ordered tie-break (matches jax.lax.top_k semantics).
// ---------------------------------------------------------------------------

namespace {

constexpr int B_  = 32;
constexpr int N_  = 2048;
constexpr int NT  = B_ * N_;        // 65536
constexpr int EPG = 16384;
constexpr int E_  = B_ * EPG;       // 524288
constexpr int NFE = 128;            // features / hidden
constexpr int NCLS = 10;

__global__ void k_fill(float* __restrict__ p, float v, int n) {
  int i = blockIdx.x * blockDim.x + threadIdx.x;
  if (i < n) p[i] = v;
}

// ---- CSR build -------------------------------------------------------------
__global__ void k_count(const int* __restrict__ dst, int* __restrict__ cnt) {
  int e = blockIdx.x * 256 + threadIdx.x;
  if (e < E_) atomicAdd(&cnt[dst[e]], 1);
}

__global__ void k_scan1(const int* __restrict__ cnt, int* __restrict__ off,
                        int* __restrict__ bsum) {
  __shared__ int s[256];
  int t = threadIdx.x;
  int i = blockIdx.x * 256 + t;
  int v = cnt[i];
  s[t] = v;
  __syncthreads();
  for (int d = 1; d < 256; d <<= 1) {
    int add = (t >= d) ? s[t - d] : 0;
    __syncthreads();
    s[t] += add;
    __syncthreads();
  }
  off[i] = s[t] - v;  // exclusive
  if (t == 255) bsum[blockIdx.x] = s[255];
}

__global__ void k_scan2(int* __restrict__ bsum) {
  __shared__ int s[256];
  int t = threadIdx.x;
  int v = bsum[t];
  s[t] = v;
  __syncthreads();
  for (int d = 1; d < 256; d <<= 1) {
    int add = (t >= d) ? s[t - d] : 0;
    __syncthreads();
    s[t] += add;
    __syncthreads();
  }
  bsum[t] = s[t] - v;  // exclusive over block sums
}

__global__ void k_scan3(int* __restrict__ off, const int* __restrict__ bsum,
                        int* __restrict__ cursor) {
  int i = blockIdx.x * 256 + threadIdx.x;
  int v = off[i] + bsum[blockIdx.x];
  off[i] = v;
  cursor[i] = v;
  if (i == NT - 1) off[NT] = E_;
}

__global__ void k_fill_eid(const int* __restrict__ dst, int* __restrict__ cursor,
                           int* __restrict__ eid) {
  int e = blockIdx.x * 256 + threadIdx.x;
  if (e < E_) {
    int p = atomicAdd(&cursor[dst[e]], 1);
    eid[p] = e;
  }
}

// ---- dense matmul: C[NT x 128] = A[NT x 128] @ W[128 x 128] ---------------
// block 256 threads, 64-row tile; per-thread 4 rows x 8 cols.
__global__ __launch_bounds__(256) void k_matmul(const float* __restrict__ A,
                                                const float* __restrict__ W,
                                                float* __restrict__ C) {
  __shared__ float As[64][33];   // [row][k-chunk] (+1 pad)
  __shared__ float Ws[32][128];  // [k-chunk][col]
  const int row0 = blockIdx.x * 64;
  const int colq = threadIdx.x & 15;   // 16 groups x 8 cols
  const int rowq = threadIdx.x >> 4;   // 16 groups x 4 rows
  float acc[4][8] = {};
  for (int k0 = 0; k0 < 128; k0 += 32) {
    {
      int r = threadIdx.x >> 5;        // 0..7
      int kk = threadIdx.x & 31;
#pragma unroll
      for (int it = 0; it < 8; ++it)
        As[r + 8 * it][kk] = A[(row0 + r + 8 * it) * 128 + k0 + kk];
    }
    for (int i = threadIdx.x; i < 32 * 128; i += 256)
      Ws[i >> 7][i & 127] = W[(k0 + (i >> 7)) * 128 + (i & 127)];
    __syncthreads();
#pragma unroll
    for (int kk = 0; kk < 32; ++kk) {
      float av[4];
#pragma unroll
      for (int r = 0; r < 4; ++r) av[r] = As[4 * rowq + r][kk];
#pragma unroll
      for (int j = 0; j < 8; ++j) {
        float wv = Ws[kk][8 * colq + j];
#pragma unroll
        for (int r = 0; r < 4; ++r) acc[r][j] += av[r] * wv;
      }
    }
    __syncthreads();
  }
#pragma unroll
  for (int r = 0; r < 4; ++r)
#pragma unroll
    for (int j = 0; j < 8; ++j)
      C[(row0 + 4 * rowq + r) * 128 + 8 * colq + j] = acc[r][j];
}

// ---- degree / dinv / self-loop weight -------------------------------------
__global__ void k_deg(const int* __restrict__ off, const int* __restrict__ eid,
                      const float* __restrict__ emask, const float* __restrict__ nmask,
                      float* __restrict__ dinv, float* __restrict__ selfw) {
  int i = blockIdx.x * 256 + threadIdx.x;
  if (i >= NT) return;
  float nm = nmask[i];
  float d = nm;
  int s = off[i], en = off[i + 1];
  for (int j = s; j < en; ++j) d += emask[eid[j]];
  float di = (d > 0.f) ? (1.0f / sqrtf(d)) : 0.f;
  dinv[i] = di;
  selfw[i] = di * di * nm;
}

__global__ void k_coef(const int* __restrict__ src, const int* __restrict__ dst,
                       const float* __restrict__ emask, const float* __restrict__ dinv,
                       float* __restrict__ coef) {
  int e = blockIdx.x * 256 + threadIdx.x;
  if (e < E_) coef[e] = dinv[src[e]] * dinv[dst[e]] * emask[e];
}

// ---- feature aggregation (gather over incoming edges) + self-loop + bias --
__global__ __launch_bounds__(256) void k_agg(const float* __restrict__ t,
                                             const float* __restrict__ coef,
                                             const int* __restrict__ off,
                                             const int* __restrict__ eid,
                                             const int* __restrict__ src,
                                             const float* __restrict__ selfw,
                                             const float* __restrict__ bias,
                                             float* __restrict__ h) {
  int node = blockIdx.x * 2 + (threadIdx.x >> 7);
  int f = threadIdx.x & 127;
  float acc = selfw[node] * t[node * 128 + f];
  int s = off[node], en = off[node + 1];
  for (int j = s; j < en; ++j) {
    int e = eid[j];
    float c = coef[e];
    if (c != 0.f) acc += c * t[src[e] * 128 + f];
  }
  acc += bias[f];
  h[node * 128 + f] = fmaxf(acc, 0.f);  // all three conv layers are relu'd
}

// ---- score matvec: t1 = h @ Wp (128 -> 1) ---------------------------------
__global__ __launch_bounds__(256) void k_scorevec(const float* __restrict__ h,
                                                  const float* __restrict__ Wp,
                                                  float* __restrict__ t1) {
  __shared__ float w[128];
  if (threadIdx.x < 128) w[threadIdx.x] = Wp[threadIdx.x];
  __syncthreads();
  int wv = threadIdx.x >> 6;
  int lane = threadIdx.x & 63;
  int node = blockIdx.x * 4 + wv;
  float v = h[node * 128 + lane] * w[lane] + h[node * 128 + 64 + lane] * w[64 + lane];
#pragma unroll
  for (int o = 32; o > 0; o >>= 1) v += __shfl_down(v, o);
  if (lane == 0) t1[node] = v;
}

__global__ void k_sagg(const float* __restrict__ t1, const float* __restrict__ coef,
                       const int* __restrict__ off, const int* __restrict__ eid,
                       const int* __restrict__ src, const float* __restrict__ selfw,
                       const float* __restrict__ bp, float* __restrict__ score) {
  int i = blockIdx.x * 256 + threadIdx.x;
  if (i >= NT) return;
  float s = selfw[i] * t1[i];
  int a = off[i], b = off[i + 1];
  for (int j = a; j < b; ++j) {
    int e = eid[j];
    float c = coef[e];
    if (c != 0.f) s += c * t1[src[e]];
  }
  score[i] = s + bp[0];
}

// ---- per-graph top-k: threshold via bitonic sort, tie-break by index ------
__global__ __launch_bounds__(1024) void k_topk(const float* __restrict__ score,
                                               float* __restrict__ nmask,
                                               float* __restrict__ scale, int k) {
  __shared__ float s[2048];
  __shared__ unsigned int ebits[64];
  __shared__ float Tsh;
  __shared__ int cgt_sh;
  const int g = blockIdx.x, t = threadIdx.x;
  const int n0 = g * N_ + t, n1 = n0 + 1024;
  float raw0 = score[n0], raw1 = score[n1];
  float ms0 = (nmask[n0] > 0.f) ? raw0 : -INFINITY;
  float ms1 = (nmask[n1] > 0.f) ? raw1 : -INFINITY;
  s[t] = ms0;
  s[t + 1024] = ms1;
  if (t < 64) ebits[t] = 0u;
  __syncthreads();
  // bitonic sort, descending
  for (int size = 2; size <= 2048; size <<= 1) {
    for (int stride = size >> 1; stride > 0; stride >>= 1) {
#pragma unroll
      for (int q = 0; q < 2; ++q) {
        int i = t + q * 1024;
        int j = i ^ stride;
        if (j > i) {
          float a = s[i], b = s[j];
          bool lowSeg = (i & size) == 0;
          if ((lowSeg && a < b) || (!lowSeg && a > b)) { s[i] = b; s[j] = a; }
        }
      }
      __syncthreads();
    }
  }
  if (t == 0) {
    float T = s[k - 1];
    Tsh = T;
    int lo = 0, hi = 2048;  // first index with s[i] <= T  == count of (> T)
    while (lo < hi) {
      int mid = (lo + hi) >> 1;
      if (s[mid] > T) lo = mid + 1; else hi = mid;
    }
    cgt_sh = lo;
  }
  __syncthreads();
  const float T = Tsh;
  const int need = k - cgt_sh;
  if (ms0 == T) atomicOr(&ebits[t >> 5], 1u << (t & 31));
  if (ms1 == T) atomicOr(&ebits[(t + 1024) >> 5], 1u << (t & 31));
  __syncthreads();
  float kp0 = (ms0 > T) ? 1.f : 0.f;
  if (ms0 == T) {
    int w = t >> 5;
    int rank = __popc(ebits[w] & ((1u << (t & 31)) - 1u));
    for (int u = 0; u < w; ++u) rank += __popc(ebits[u]);
    kp0 = (rank < need) ? 1.f : 0.f;
  }
  float kp1 = (ms1 > T) ? 1.f : 0.f;
  if (ms1 == T) {
    int n = t + 1024, w = n >> 5;
    int rank = __popc(ebits[w] & ((1u << (n & 31)) - 1u));
    for (int u = 0; u < w; ++u) rank += __popc(ebits[u]);
    kp1 = (rank < need) ? 1.f : 0.f;
  }
  nmask[n0] = kp0;
  nmask[n1] = kp1;
  scale[n0] = kp0 * tanhf(raw0);
  scale[n1] = kp1 * tanhf(raw1);
}

__global__ void k_apply(float4* __restrict__ h4, const float* __restrict__ scale) {
  int idx = blockIdx.x * 256 + threadIdx.x;  // NT*32 float4s
  if (idx < NT * 32) {
    float sc = scale[idx >> 5];
    float4 v = h4[idx];
    v.x *= sc; v.y *= sc; v.z *= sc; v.w *= sc;
    h4[idx] = v;
  }
}

__global__ void k_eupd(const int* __restrict__ src, const int* __restrict__ dst,
                       const float* __restrict__ nmask, float* __restrict__ emask) {
  int e = blockIdx.x * 256 + threadIdx.x;
  if (e < E_) emask[e] *= nmask[src[e]] * nmask[dst[e]];
}

// ---- readout: [max, mean] over active nodes -------------------------------
__global__ void k_readout1(const float* __restrict__ h, const float* __restrict__ nmask,
                           float* __restrict__ pmx, float* __restrict__ psm) {
  int g = blockIdx.x, part = blockIdx.y, f = threadIdx.x;
  float mx = -INFINITY, sm = 0.f;
  int nbeg = part * 256, nend = nbeg + 256;
  for (int n = nbeg; n < nend; ++n) {
    int node = g * N_ + n;
    float m = nmask[node];
    float v = h[node * 128 + f];
    if (m > 0.f) { mx = fmaxf(mx, v); sm += v; }
  }
  pmx[(g * 8 + part) * 128 + f] = mx;
  psm[(g * 8 + part) * 128 + f] = sm;
}

__global__ void k_readout2(const float* __restrict__ pmx, const float* __restrict__ psm,
                           float* __restrict__ gacc, float invk) {
  int g = blockIdx.x, f = threadIdx.x;
  float mx = -INFINITY, sm = 0.f;
  for (int p = 0; p < 8; ++p) {
    mx = fmaxf(mx, pmx[(g * 8 + p) * 128 + f]);
    sm += psm[(g * 8 + p) * 128 + f];
  }
  gacc[g * 256 + f] += mx;
  gacc[g * 256 + 128 + f] += sm * invk;
}

// ---- MLP head + log_softmax ------------------------------------------------
__global__ __launch_bounds__(128) void k_mlp(const float* __restrict__ gacc,
                                             const float* __restrict__ W1,
                                             const float* __restrict__ b1,
                                             const float* __restrict__ W2,
                                             const float* __restrict__ b2,
                                             const float* __restrict__ W3,
                                             const float* __restrict__ b3,
                                             float* __restrict__ out) {
  __shared__ float gr[256], o1[128], o2[64], o3[NCLS];
  int g = blockIdx.x, t = threadIdx.x;
  gr[t] = gacc[g * 256 + t];
  gr[t + 128] = gacc[g * 256 + 128 + t];
  __syncthreads();
  float a = b1[t];
  for (int kk = 0; kk < 256; ++kk) a += gr[kk] * W1[kk * 128 + t];
  o1[t] = fmaxf(a, 0.f);
  __syncthreads();
  if (t < 64) {
    float a2 = b2[t];
    for (int kk = 0; kk < 128; ++kk) a2 += o1[kk] * W2[kk * 64 + t];
    o2[t] = fmaxf(a2, 0.f);
  }
  __syncthreads();
  if (t < NCLS) {
    float a3 = b3[t];
    for (int kk = 0; kk < 64; ++kk) a3 += o2[kk] * W3[kk * NCLS + t];
    o3[t] = a3;
  }
  __syncthreads();
  if (t == 0) {
    float m = -INFINITY;
    for (int c = 0; c < NCLS; ++c) m = fmaxf(m, o3[c]);
    float sum = 0.f;
    for (int c = 0; c < NCLS; ++c) sum += expf(o3[c] - m);
    float lse = logf(sum);
    for (int c = 0; c < NCLS; ++c) out[g * NCLS + c] = o3[c] - m - lse;
  }
}

}  // namespace

extern "C" void kernel_launch(void* const* d_in, const int* in_sizes, int n_in,
                              void* d_out, int out_size, void* d_ws, size_t ws_size,
                              hipStream_t stream) {
  const float* x = (const float*)d_in[0];
  const int* ei = (const int*)d_in[1];
  const int* src = ei;
  const int* dst = ei + E_;
  const float* Wl[3]  = {(const float*)d_in[3], (const float*)d_in[7], (const float*)d_in[11]};
  const float* bl[3]  = {(const float*)d_in[4], (const float*)d_in[8], (const float*)d_in[12]};
  const float* Wpl[3] = {(const float*)d_in[5], (const float*)d_in[9], (const float*)d_in[13]};
  const float* bpl[3] = {(const float*)d_in[6], (const float*)d_in[10], (const float*)d_in[14]};
  const float* l1W = (const float*)d_in[15];
  const float* l1b = (const float*)d_in[16];
  const float* l2W = (const float*)d_in[17];
  const float* l2b = (const float*)d_in[18];
  const float* l3W = (const float*)d_in[19];
  const float* l3b = (const float*)d_in[20];

  char* p = (char*)d_ws;
  auto alloc = [&](size_t bytes) -> void* {
    void* r = (void*)p;
    p += (bytes + 255) & ~size_t(255);
    return r;
  };
  float* h      = (float*)alloc((size_t)NT * 128 * 4);
  float* t      = (float*)alloc((size_t)NT * 128 * 4);
  float* dinv   = (float*)alloc(NT * 4);
  float* selfw  = (float*)alloc(NT * 4);
  float* t1     = (float*)alloc(NT * 4);
  float* score  = (float*)alloc(NT * 4);
  float* scale  = (float*)alloc(NT * 4);
  float* nmask  = (float*)alloc(NT * 4);
  float* emask  = (float*)alloc(E_ * 4);
  float* coef   = (float*)alloc(E_ * 4);
  int*   off    = (int*)alloc((NT + 1) * 4);
  int*   cnt    = (int*)alloc(NT * 4);
  int*   cursor = (int*)alloc(NT * 4);
  int*   eid    = (int*)alloc(E_ * 4);
  int*   bsum   = (int*)alloc(256 * 4);
  float* pmx    = (float*)alloc(B_ * 8 * 128 * 4);
  float* psm    = (float*)alloc(B_ * 8 * 128 * 4);
  float* gacc   = (float*)alloc(B_ * 256 * 4);

  const int K[3] = {1024, 512, 256};

  hipMemsetAsync(cnt, 0, NT * 4, stream);
  hipMemsetAsync(gacc, 0, B_ * 256 * 4, stream);
  k_fill<<<E_ / 256, 256, 0, stream>>>(emask, 1.f, E_);
  k_fill<<<NT / 256, 256, 0, stream>>>(nmask, 1.f, NT);

  // CSR (incoming edges per node), built once — masks don't change topology.
  k_count<<<E_ / 256, 256, 0, stream>>>(dst, cnt);
  k_scan1<<<256, 256, 0, stream>>>(cnt, off, bsum);
  k_scan2<<<1, 256, 0, stream>>>(bsum);
  k_scan3<<<256, 256, 0, stream>>>(off, bsum, cursor);
  k_fill_eid<<<E_ / 256, 256, 0, stream>>>(dst, cursor, eid);

  const float* inF = x;
  for (int l = 0; l < 3; ++l) {
    k_matmul<<<NT / 64, 256, 0, stream>>>(inF, Wl[l], t);
    k_deg<<<NT / 256, 256, 0, stream>>>(off, eid, emask, nmask, dinv, selfw);
    k_coef<<<E_ / 256, 256, 0, stream>>>(src, dst, emask, dinv, coef);
    k_agg<<<NT / 2, 256, 0, stream>>>(t, coef, off, eid, src, selfw, bl[l], h);
    k_scorevec<<<NT / 4, 256, 0, stream>>>(h, Wpl[l], t1);
    k_sagg<<<NT / 256, 256, 0, stream>>>(t1, coef, off, eid, src, selfw, bpl[l], score);
    k_topk<<<B_, 1024, 0, stream>>>(score, nmask, scale, K[l]);
    k_apply<<<NT * 32 / 256, 256, 0, stream>>>((float4*)h, scale);
    k_eupd<<<E_ / 256, 256, 0, stream>>>(src, dst, nmask, emask);
    k_readout1<<<dim3(B_, 8), 128, 0, stream>>>(h, nmask, pmx, psm);
    k_readout2<<<B_, 128, 0, stream>>>(pmx, psm, gacc, 1.f / (float)K[l]);
    inF = h;
  }
  k_mlp<<<B_, 128, 0, stream>>>(gacc, l1W, l1b, l2W, l2b, l3W, l3b, (float*)d_out);
}

// Round 2
// 581.353 us; speedup vs baseline: 1.7628x; 1.7628x over previous
//
#include <hip/hip_runtime.h>
#include <math.h>

// ---------------------------------------------------------------------------
// SAGPool GNN forward: 3x [GCNConv -> SAGPool(top-k) -> readout] + MLP head.
// B=32 graphs x N=2048 nodes; E=524288; 128 feats; K = 1024/512/256.
// R2 changes vs R1 (k_agg was latency-bound: VALUBusy 12%, HBM 10%, occ 75%):
//   - CSR-permuted edge arrays (srcp/dstp/coefp in slot order): the agg loop
//     is a 1-deep chain (pair load -> row gather), unrolled x4 -> 4 gathers
//     in flight instead of 1.
//   - emask deleted: emask[e] == nmask[src]*nmask[dst] (keep sets shrink
//     monotonically); coef = dinv[src]*dinv[dst] (dinv=0 for dead nodes).
//   - score matvec fused into k_agg epilogue (saves 32MB h re-read);
//     k_apply deleted (scale folded into next matmul A-load and readout).
//   - matmul: transposed A-tile, ds_read_b128 inner loop, float4 stores.
// ---------------------------------------------------------------------------

namespace {

constexpr int B_  = 32;
constexpr int N_  = 2048;
constexpr int NT  = B_ * N_;        // 65536
constexpr int EPG = 16384;
constexpr int E_  = B_ * EPG;       // 524288
constexpr int NCLS = 10;

__global__ void k_fill(float* __restrict__ p, float v, int n) {
  int i = blockIdx.x * blockDim.x + threadIdx.x;
  if (i < n) p[i] = v;
}

// ---- CSR build -------------------------------------------------------------
__global__ void k_count(const int* __restrict__ dst, int* __restrict__ cnt) {
  int e = blockIdx.x * 256 + threadIdx.x;
  if (e < E_) atomicAdd(&cnt[dst[e]], 1);
}

__global__ void k_scan1(const int* __restrict__ cnt, int* __restrict__ off,
                        int* __restrict__ bsum) {
  __shared__ int s[256];
  int t = threadIdx.x;
  int i = blockIdx.x * 256 + t;
  int v = cnt[i];
  s[t] = v;
  __syncthreads();
  for (int d = 1; d < 256; d <<= 1) {
    int add = (t >= d) ? s[t - d] : 0;
    __syncthreads();
    s[t] += add;
    __syncthreads();
  }
  off[i] = s[t] - v;  // exclusive
  if (t == 255) bsum[blockIdx.x] = s[255];
}

__global__ void k_scan2(int* __restrict__ bsum) {
  __shared__ int s[256];
  int t = threadIdx.x;
  int v = bsum[t];
  s[t] = v;
  __syncthreads();
  for (int d = 1; d < 256; d <<= 1) {
    int add = (t >= d) ? s[t - d] : 0;
    __syncthreads();
    s[t] += add;
    __syncthreads();
  }
  bsum[t] = s[t] - v;
}

__global__ void k_scan3(int* __restrict__ off, const int* __restrict__ bsum,
                        int* __restrict__ cursor) {
  int i = blockIdx.x * 256 + threadIdx.x;
  int v = off[i] + bsum[blockIdx.x];
  off[i] = v;
  cursor[i] = v;
  if (i == NT - 1) off[NT] = E_;
}

__global__ void k_fill_eid(const int* __restrict__ dst, int* __restrict__ cursor,
                           int* __restrict__ eid) {
  int e = blockIdx.x * 256 + threadIdx.x;
  if (e < E_) {
    int p = atomicAdd(&cursor[dst[e]], 1);
    eid[p] = e;
  }
}

// slot-order edge endpoints: removes the eid[] indirection from all hot loops
__global__ void k_permute(const int* __restrict__ eid, const int* __restrict__ src,
                          const int* __restrict__ dst, int* __restrict__ srcp,
                          int* __restrict__ dstp) {
  int j = blockIdx.x * 256 + threadIdx.x;
  if (j < E_) {
    int e = eid[j];
    srcp[j] = src[e];
    dstp[j] = dst[e];
  }
}

// ---- dense matmul: C[NT x 128] = (scale .* A)[NT x 128] @ W[128 x 128] ----
// block 256; 64-row tile; A-tile stored transposed -> b128 LDS reads.
__global__ __launch_bounds__(256) void k_matmul(const float* __restrict__ A,
                                                const float* __restrict__ scale,
                                                const float* __restrict__ W,
                                                float* __restrict__ C) {
  __shared__ float Ast[32][68];  // [k][row], pad 68 (16B-aligned rows, 4-way store conflict only)
  __shared__ float Ws[32][128];  // [k][col]
  const int row0 = blockIdx.x * 64;
  const int tid = threadIdx.x;
  const int rowq = tid >> 4;   // 0..15 -> rows 4*rowq..+3
  const int colq = tid & 15;   // 0..15 -> cols 8*colq..+7
  float acc[4][8] = {};
  for (int k0 = 0; k0 < 128; k0 += 32) {
    {
      int kk = tid & 31, rr = tid >> 5;  // rr 0..7
#pragma unroll
      for (int it = 0; it < 8; ++it) {
        int r = rr + 8 * it;
        Ast[kk][r] = A[(size_t)(row0 + r) * 128 + k0 + kk] * scale[row0 + r];
      }
    }
    {
      const float4* W4 = (const float4*)W;
      float4* Ws4 = (float4*)Ws;
#pragma unroll
      for (int it = 0; it < 4; ++it)
        Ws4[tid + 256 * it] = W4[k0 * 32 + tid + 256 * it];
    }
    __syncthreads();
#pragma unroll
    for (int kk = 0; kk < 32; ++kk) {
      float4 av = *(const float4*)&Ast[kk][4 * rowq];
      const float4* wrow = (const float4*)&Ws[kk][0];
      float4 w0 = wrow[2 * colq], w1 = wrow[2 * colq + 1];
      float a[4] = {av.x, av.y, av.z, av.w};
      float w[8] = {w0.x, w0.y, w0.z, w0.w, w1.x, w1.y, w1.z, w1.w};
#pragma unroll
      for (int r = 0; r < 4; ++r)
#pragma unroll
        for (int j = 0; j < 8; ++j) acc[r][j] += a[r] * w[j];
    }
    __syncthreads();
  }
#pragma unroll
  for (int r = 0; r < 4; ++r) {
    float4* Crow = (float4*)&C[(size_t)(row0 + 4 * rowq + r) * 128 + 8 * colq];
    Crow[0] = make_float4(acc[r][0], acc[r][1], acc[r][2], acc[r][3]);
    Crow[1] = make_float4(acc[r][4], acc[r][5], acc[r][6], acc[r][7]);
  }
}

// ---- degree / dinv / self-loop weight (emask == nmask[src]*nmask[dst]) ----
__global__ void k_deg(const int* __restrict__ off, const int* __restrict__ srcp,
                      const float* __restrict__ nmask,
                      float* __restrict__ dinv, float* __restrict__ selfw) {
  int i = blockIdx.x * 256 + threadIdx.x;
  if (i >= NT) return;
  float nm = nmask[i];
  int s = off[i], en = off[i + 1];
  float d = 1.f;  // self (only meaningful when nm>0)
  int j = s;
  float d0 = 0.f, d1 = 0.f, d2 = 0.f, d3 = 0.f;
  for (; j + 4 <= en; j += 4) {
    int s0 = srcp[j], s1 = srcp[j + 1], s2 = srcp[j + 2], s3 = srcp[j + 3];
    d0 += nmask[s0]; d1 += nmask[s1]; d2 += nmask[s2]; d3 += nmask[s3];
  }
  for (; j < en; ++j) d0 += nmask[srcp[j]];
  d += d0 + d1 + d2 + d3;
  float di = (nm > 0.f) ? (1.0f / sqrtf(d)) : 0.f;
  dinv[i] = di;
  selfw[i] = di * di * nm;
}

__global__ void k_coef(const int* __restrict__ srcp, const int* __restrict__ dstp,
                       const float* __restrict__ dinv, float* __restrict__ coefp) {
  int j = blockIdx.x * 256 + threadIdx.x;
  if (j < E_) coefp[j] = dinv[srcp[j]] * dinv[dstp[j]];
}

// ---- feature aggregation (gather) + bias + relu + fused score matvec ------
// 32 lanes per node (float4 feats); 8 nodes per 256-block; edge loop unroll x4.
__global__ __launch_bounds__(256) void k_agg(const float4* __restrict__ t4,
                                             const float* __restrict__ coefp,
                                             const int* __restrict__ off,
                                             const int* __restrict__ srcp,
                                             const float* __restrict__ selfw,
                                             const float* __restrict__ bias,
                                             const float* __restrict__ Wp,
                                             float4* __restrict__ h4,
                                             float* __restrict__ t1) {
  const int node = blockIdx.x * 8 + (threadIdx.x >> 5);
  const int lane = threadIdx.x & 31;
  float sw = selfw[node];
  float4 self = t4[(size_t)node * 32 + lane];
  float4 acc = make_float4(sw * self.x, sw * self.y, sw * self.z, sw * self.w);
  int s = off[node], en = off[node + 1];
  int j = s;
  for (; j + 4 <= en; j += 4) {
    int s0 = srcp[j], s1 = srcp[j + 1], s2 = srcp[j + 2], s3 = srcp[j + 3];
    float c0 = coefp[j], c1 = coefp[j + 1], c2 = coefp[j + 2], c3 = coefp[j + 3];
    float4 r0 = t4[(size_t)s0 * 32 + lane];
    float4 r1 = t4[(size_t)s1 * 32 + lane];
    float4 r2 = t4[(size_t)s2 * 32 + lane];
    float4 r3 = t4[(size_t)s3 * 32 + lane];
    acc.x += c0 * r0.x + c1 * r1.x + c2 * r2.x + c3 * r3.x;
    acc.y += c0 * r0.y + c1 * r1.y + c2 * r2.y + c3 * r3.y;
    acc.z += c0 * r0.z + c1 * r1.z + c2 * r2.z + c3 * r3.z;
    acc.w += c0 * r0.w + c1 * r1.w + c2 * r2.w + c3 * r3.w;
  }
  for (; j < en; ++j) {
    int s0 = srcp[j];
    float c0 = coefp[j];
    float4 r0 = t4[(size_t)s0 * 32 + lane];
    acc.x += c0 * r0.x; acc.y += c0 * r0.y; acc.z += c0 * r0.z; acc.w += c0 * r0.w;
  }
  float4 b4 = ((const float4*)bias)[lane];
  acc.x = fmaxf(acc.x + b4.x, 0.f);
  acc.y = fmaxf(acc.y + b4.y, 0.f);
  acc.z = fmaxf(acc.z + b4.z, 0.f);
  acc.w = fmaxf(acc.w + b4.w, 0.f);
  h4[(size_t)node * 32 + lane] = acc;
  // fused score matvec: t1[node] = dot(h_row, Wp)
  float4 wp = ((const float4*)Wp)[lane];
  float part = acc.x * wp.x + acc.y * wp.y + acc.z * wp.z + acc.w * wp.w;
#pragma unroll
  for (int o = 16; o > 0; o >>= 1) part += __shfl_down(part, o, 32);
  if (lane == 0) t1[node] = part;
}

// ---- score aggregation ----------------------------------------------------
__global__ void k_sagg(const float* __restrict__ t1, const float* __restrict__ coefp,
                       const int* __restrict__ off, const int* __restrict__ srcp,
                       const float* __restrict__ selfw,
                       const float* __restrict__ bp, float* __restrict__ score) {
  int i = blockIdx.x * 256 + threadIdx.x;
  if (i >= NT) return;
  float a0 = selfw[i] * t1[i], a1 = 0.f, a2 = 0.f, a3 = 0.f;
  int s = off[i], en = off[i + 1];
  int j = s;
  for (; j + 4 <= en; j += 4) {
    int s0 = srcp[j], s1 = srcp[j + 1], s2 = srcp[j + 2], s3 = srcp[j + 3];
    float c0 = coefp[j], c1 = coefp[j + 1], c2 = coefp[j + 2], c3 = coefp[j + 3];
    a0 += c0 * t1[s0]; a1 += c1 * t1[s1]; a2 += c2 * t1[s2]; a3 += c3 * t1[s3];
  }
  for (; j < en; ++j) a0 += coefp[j] * t1[srcp[j]];
  score[i] = a0 + a1 + a2 + a3 + bp[0];
}

// ---- per-graph top-k: bitonic sort + threshold, tie-break by index --------
__global__ __launch_bounds__(1024) void k_topk(const float* __restrict__ score,
                                               float* __restrict__ nmask,
                                               float* __restrict__ scale, int k) {
  __shared__ float s[2048];
  __shared__ unsigned int ebits[64];
  __shared__ float Tsh;
  __shared__ int cgt_sh;
  const int g = blockIdx.x, t = threadIdx.x;
  const int n0 = g * N_ + t, n1 = n0 + 1024;
  float raw0 = score[n0], raw1 = score[n1];
  float ms0 = (nmask[n0] > 0.f) ? raw0 : -INFINITY;
  float ms1 = (nmask[n1] > 0.f) ? raw1 : -INFINITY;
  s[t] = ms0;
  s[t + 1024] = ms1;
  if (t < 64) ebits[t] = 0u;
  __syncthreads();
  for (int size = 2; size <= 2048; size <<= 1) {
    for (int stride = size >> 1; stride > 0; stride >>= 1) {
#pragma unroll
      for (int q = 0; q < 2; ++q) {
        int i = t + q * 1024;
        int j = i ^ stride;
        if (j > i) {
          float a = s[i], b = s[j];
          bool lowSeg = (i & size) == 0;
          if ((lowSeg && a < b) || (!lowSeg && a > b)) { s[i] = b; s[j] = a; }
        }
      }
      __syncthreads();
    }
  }
  if (t == 0) {
    float T = s[k - 1];
    Tsh = T;
    int lo = 0, hi = 2048;  // count of (> T)
    while (lo < hi) {
      int mid = (lo + hi) >> 1;
      if (s[mid] > T) lo = mid + 1; else hi = mid;
    }
    cgt_sh = lo;
  }
  __syncthreads();
  const float T = Tsh;
  const int need = k - cgt_sh;
  if (ms0 == T) atomicOr(&ebits[t >> 5], 1u << (t & 31));
  if (ms1 == T) atomicOr(&ebits[(t + 1024) >> 5], 1u << (t & 31));
  __syncthreads();
  float kp0 = (ms0 > T) ? 1.f : 0.f;
  if (ms0 == T) {
    int w = t >> 5;
    int rank = __popc(ebits[w] & ((1u << (t & 31)) - 1u));
    for (int u = 0; u < w; ++u) rank += __popc(ebits[u]);
    kp0 = (rank < need) ? 1.f : 0.f;
  }
  float kp1 = (ms1 > T) ? 1.f : 0.f;
  if (ms1 == T) {
    int n = t + 1024, w = n >> 5;
    int rank = __popc(ebits[w] & ((1u << (n & 31)) - 1u));
    for (int u = 0; u < w; ++u) rank += __popc(ebits[u]);
    kp1 = (rank < need) ? 1.f : 0.f;
  }
  nmask[n0] = kp0;
  nmask[n1] = kp1;
  scale[n0] = kp0 * tanhf(raw0);
  scale[n1] = kp1 * tanhf(raw1);
}

// ---- readout: [max, mean] over active nodes of scale.*h -------------------
__global__ void k_readout1(const float* __restrict__ h, const float* __restrict__ scale,
                           const float* __restrict__ nmask,
                           float* __restrict__ pmx, float* __restrict__ psm) {
  int g = blockIdx.x, part = blockIdx.y, f = threadIdx.x;
  float mx = -INFINITY, sm = 0.f;
  int nbeg = part * 256, nend = nbeg + 256;
  for (int n = nbeg; n < nend; ++n) {
    int node = g * N_ + n;
    float m = nmask[node];
    if (m > 0.f) {
      float v = h[(size_t)node * 128 + f] * scale[node];
      mx = fmaxf(mx, v);
      sm += v;
    }
  }
  pmx[(g * 8 + part) * 128 + f] = mx;
  psm[(g * 8 + part) * 128 + f] = sm;
}

__global__ void k_readout2(const float* __restrict__ pmx, const float* __restrict__ psm,
                           float* __restrict__ gacc, float invk) {
  int g = blockIdx.x, f = threadIdx.x;
  float mx = -INFINITY, sm = 0.f;
  for (int p = 0; p < 8; ++p) {
    mx = fmaxf(mx, pmx[(g * 8 + p) * 128 + f]);
    sm += psm[(g * 8 + p) * 128 + f];
  }
  gacc[g * 256 + f] += mx;
  gacc[g * 256 + 128 + f] += sm * invk;
}

// ---- MLP head + log_softmax ------------------------------------------------
__global__ __launch_bounds__(128) void k_mlp(const float* __restrict__ gacc,
                                             const float* __restrict__ W1,
                                             const float* __restrict__ b1,
                                             const float* __restrict__ W2,
                                             const float* __restrict__ b2,
                                             const float* __restrict__ W3,
                                             const float* __restrict__ b3,
                                             float* __restrict__ out) {
  __shared__ float gr[256], o1[128], o2[64], o3[NCLS];
  int g = blockIdx.x, t = threadIdx.x;
  gr[t] = gacc[g * 256 + t];
  gr[t + 128] = gacc[g * 256 + 128 + t];
  __syncthreads();
  float a = b1[t];
  for (int kk = 0; kk < 256; ++kk) a += gr[kk] * W1[kk * 128 + t];
  o1[t] = fmaxf(a, 0.f);
  __syncthreads();
  if (t < 64) {
    float a2 = b2[t];
    for (int kk = 0; kk < 128; ++kk) a2 += o1[kk] * W2[kk * 64 + t];
    o2[t] = fmaxf(a2, 0.f);
  }
  __syncthreads();
  if (t < NCLS) {
    float a3 = b3[t];
    for (int kk = 0; kk < 64; ++kk) a3 += o2[kk] * W3[kk * NCLS + t];
    o3[t] = a3;
  }
  __syncthreads();
  if (t == 0) {
    float m = -INFINITY;
    for (int c = 0; c < NCLS; ++c) m = fmaxf(m, o3[c]);
    float sum = 0.f;
    for (int c = 0; c < NCLS; ++c) sum += expf(o3[c] - m);
    float lse = logf(sum);
    for (int c = 0; c < NCLS; ++c) out[g * NCLS + c] = o3[c] - m - lse;
  }
}

}  // namespace

extern "C" void kernel_launch(void* const* d_in, const int* in_sizes, int n_in,
                              void* d_out, int out_size, void* d_ws, size_t ws_size,
                              hipStream_t stream) {
  const float* x = (const float*)d_in[0];
  const int* ei = (const int*)d_in[1];
  const int* src = ei;
  const int* dst = ei + E_;
  const float* Wl[3]  = {(const float*)d_in[3], (const float*)d_in[7], (const float*)d_in[11]};
  const float* bl[3]  = {(const float*)d_in[4], (const float*)d_in[8], (const float*)d_in[12]};
  const float* Wpl[3] = {(const float*)d_in[5], (const float*)d_in[9], (const float*)d_in[13]};
  const float* bpl[3] = {(const float*)d_in[6], (const float*)d_in[10], (const float*)d_in[14]};
  const float* l1W = (const float*)d_in[15];
  const float* l1b = (const float*)d_in[16];
  const float* l2W = (const float*)d_in[17];
  const float* l2b = (const float*)d_in[18];
  const float* l3W = (const float*)d_in[19];
  const float* l3b = (const float*)d_in[20];

  char* p = (char*)d_ws;
  auto alloc = [&](size_t bytes) -> void* {
    void* r = (void*)p;
    p += (bytes + 255) & ~size_t(255);
    return r;
  };
  float* h      = (float*)alloc((size_t)NT * 128 * 4);
  float* t      = (float*)alloc((size_t)NT * 128 * 4);
  float* dinv   = (float*)alloc(NT * 4);
  float* selfw  = (float*)alloc(NT * 4);
  float* t1     = (float*)alloc(NT * 4);
  float* score  = (float*)alloc(NT * 4);
  float* scale  = (float*)alloc(NT * 4);
  float* nmask  = (float*)alloc(NT * 4);
  float* coefp  = (float*)alloc(E_ * 4);
  int*   srcp   = (int*)alloc(E_ * 4);
  int*   dstp   = (int*)alloc(E_ * 4);
  int*   off    = (int*)alloc((NT + 1) * 4);
  int*   cnt    = (int*)alloc(NT * 4);
  int*   cursor = (int*)alloc(NT * 4);
  int*   eid    = (int*)alloc(E_ * 4);
  int*   bsum   = (int*)alloc(256 * 4);
  float* pmx    = (float*)alloc(B_ * 8 * 128 * 4);
  float* psm    = (float*)alloc(B_ * 8 * 128 * 4);
  float* gacc   = (float*)alloc(B_ * 256 * 4);

  const int K[3] = {1024, 512, 256};

  hipMemsetAsync(cnt, 0, NT * 4, stream);
  hipMemsetAsync(gacc, 0, B_ * 256 * 4, stream);
  k_fill<<<NT / 256, 256, 0, stream>>>(nmask, 1.f, NT);
  k_fill<<<NT / 256, 256, 0, stream>>>(scale, 1.f, NT);

  // CSR (incoming edges per node) + slot-order endpoint arrays, built once.
  k_count<<<E_ / 256, 256, 0, stream>>>(dst, cnt);
  k_scan1<<<256, 256, 0, stream>>>(cnt, off, bsum);
  k_scan2<<<1, 256, 0, stream>>>(bsum);
  k_scan3<<<256, 256, 0, stream>>>(off, bsum, cursor);
  k_fill_eid<<<E_ / 256, 256, 0, stream>>>(dst, cursor, eid);
  k_permute<<<E_ / 256, 256, 0, stream>>>(eid, src, dst, srcp, dstp);

  const float* inF = x;
  for (int l = 0; l < 3; ++l) {
    k_matmul<<<NT / 64, 256, 0, stream>>>(inF, scale, Wl[l], t);
    k_deg<<<NT / 256, 256, 0, stream>>>(off, srcp, nmask, dinv, selfw);
    k_coef<<<E_ / 256, 256, 0, stream>>>(srcp, dstp, dinv, coefp);
    k_agg<<<NT / 8, 256, 0, stream>>>((const float4*)t, coefp, off, srcp, selfw,
                                      bl[l], Wpl[l], (float4*)h, t1);
    k_sagg<<<NT / 256, 256, 0, stream>>>(t1, coefp, off, srcp, selfw, bpl[l], score);
    k_topk<<<B_, 1024, 0, stream>>>(score, nmask, scale, K[l]);
    k_readout1<<<dim3(B_, 8), 128, 0, stream>>>(h, scale, nmask, pmx, psm);
    k_readout2<<<B_, 128, 0, stream>>>(pmx, psm, gacc, 1.f / (float)K[l]);
    inF = h;
  }
  k_mlp<<<B_, 128, 0, stream>>>(gacc, l1W, l1b, l2W, l2b, l3W, l3b, (float*)d_out);
}

// Round 3
// 507.261 us; speedup vs baseline: 2.0203x; 1.1461x over previous
//
#include <hip/hip_runtime.h>
#include <math.h>

// ---------------------------------------------------------------------------
// SAGPool GNN forward: 3x [GCNConv -> SAGPool(top-k) -> readout] + MLP head.
// B=32 graphs x N=2048 nodes; E=524288; 128 feats; K = 1024/512/256.
// R3 change vs R2: k_readout1 was latency-bound (occ 4.6%, 187 GB/s, 49us).
//   Now grid (B x 32 parts) x 256 thr, float4 row reads (32 lanes/node,
//   8 node-groups, 8 iters), LDS tree reduce. Everything else unchanged.
// ---------------------------------------------------------------------------

namespace {

constexpr int B_  = 32;
constexpr int N_  = 2048;
constexpr int NT  = B_ * N_;        // 65536
constexpr int EPG = 16384;
constexpr int E_  = B_ * EPG;       // 524288
constexpr int NCLS = 10;
constexpr int RPARTS = 32;          // readout parts per graph

__global__ void k_fill(float* __restrict__ p, float v, int n) {
  int i = blockIdx.x * blockDim.x + threadIdx.x;
  if (i < n) p[i] = v;
}

// ---- CSR build -------------------------------------------------------------
__global__ void k_count(const int* __restrict__ dst, int* __restrict__ cnt) {
  int e = blockIdx.x * 256 + threadIdx.x;
  if (e < E_) atomicAdd(&cnt[dst[e]], 1);
}

__global__ void k_scan1(const int* __restrict__ cnt, int* __restrict__ off,
                        int* __restrict__ bsum) {
  __shared__ int s[256];
  int t = threadIdx.x;
  int i = blockIdx.x * 256 + t;
  int v = cnt[i];
  s[t] = v;
  __syncthreads();
  for (int d = 1; d < 256; d <<= 1) {
    int add = (t >= d) ? s[t - d] : 0;
    __syncthreads();
    s[t] += add;
    __syncthreads();
  }
  off[i] = s[t] - v;  // exclusive
  if (t == 255) bsum[blockIdx.x] = s[255];
}

__global__ void k_scan2(int* __restrict__ bsum) {
  __shared__ int s[256];
  int t = threadIdx.x;
  int v = bsum[t];
  s[t] = v;
  __syncthreads();
  for (int d = 1; d < 256; d <<= 1) {
    int add = (t >= d) ? s[t - d] : 0;
    __syncthreads();
    s[t] += add;
    __syncthreads();
  }
  bsum[t] = s[t] - v;
}

__global__ void k_scan3(int* __restrict__ off, const int* __restrict__ bsum,
                        int* __restrict__ cursor) {
  int i = blockIdx.x * 256 + threadIdx.x;
  int v = off[i] + bsum[blockIdx.x];
  off[i] = v;
  cursor[i] = v;
  if (i == NT - 1) off[NT] = E_;
}

__global__ void k_fill_eid(const int* __restrict__ dst, int* __restrict__ cursor,
                           int* __restrict__ eid) {
  int e = blockIdx.x * 256 + threadIdx.x;
  if (e < E_) {
    int p = atomicAdd(&cursor[dst[e]], 1);
    eid[p] = e;
  }
}

__global__ void k_permute(const int* __restrict__ eid, const int* __restrict__ src,
                          const int* __restrict__ dst, int* __restrict__ srcp,
                          int* __restrict__ dstp) {
  int j = blockIdx.x * 256 + threadIdx.x;
  if (j < E_) {
    int e = eid[j];
    srcp[j] = src[e];
    dstp[j] = dst[e];
  }
}

// ---- dense matmul: C[NT x 128] = (scale .* A)[NT x 128] @ W[128 x 128] ----
__global__ __launch_bounds__(256) void k_matmul(const float* __restrict__ A,
                                                const float* __restrict__ scale,
                                                const float* __restrict__ W,
                                                float* __restrict__ C) {
  __shared__ float Ast[32][68];
  __shared__ float Ws[32][128];
  const int row0 = blockIdx.x * 64;
  const int tid = threadIdx.x;
  const int rowq = tid >> 4;
  const int colq = tid & 15;
  float acc[4][8] = {};
  for (int k0 = 0; k0 < 128; k0 += 32) {
    {
      int kk = tid & 31, rr = tid >> 5;
#pragma unroll
      for (int it = 0; it < 8; ++it) {
        int r = rr + 8 * it;
        Ast[kk][r] = A[(size_t)(row0 + r) * 128 + k0 + kk] * scale[row0 + r];
      }
    }
    {
      const float4* W4 = (const float4*)W;
      float4* Ws4 = (float4*)Ws;
#pragma unroll
      for (int it = 0; it < 4; ++it)
        Ws4[tid + 256 * it] = W4[k0 * 32 + tid + 256 * it];
    }
    __syncthreads();
#pragma unroll
    for (int kk = 0; kk < 32; ++kk) {
      float4 av = *(const float4*)&Ast[kk][4 * rowq];
      const float4* wrow = (const float4*)&Ws[kk][0];
      float4 w0 = wrow[2 * colq], w1 = wrow[2 * colq + 1];
      float a[4] = {av.x, av.y, av.z, av.w};
      float w[8] = {w0.x, w0.y, w0.z, w0.w, w1.x, w1.y, w1.z, w1.w};
#pragma unroll
      for (int r = 0; r < 4; ++r)
#pragma unroll
        for (int j = 0; j < 8; ++j) acc[r][j] += a[r] * w[j];
    }
    __syncthreads();
  }
#pragma unroll
  for (int r = 0; r < 4; ++r) {
    float4* Crow = (float4*)&C[(size_t)(row0 + 4 * rowq + r) * 128 + 8 * colq];
    Crow[0] = make_float4(acc[r][0], acc[r][1], acc[r][2], acc[r][3]);
    Crow[1] = make_float4(acc[r][4], acc[r][5], acc[r][6], acc[r][7]);
  }
}

// ---- degree / dinv / self-loop weight -------------------------------------
__global__ void k_deg(const int* __restrict__ off, const int* __restrict__ srcp,
                      const float* __restrict__ nmask,
                      float* __restrict__ dinv, float* __restrict__ selfw) {
  int i = blockIdx.x * 256 + threadIdx.x;
  if (i >= NT) return;
  float nm = nmask[i];
  int s = off[i], en = off[i + 1];
  float d = 1.f;
  int j = s;
  float d0 = 0.f, d1 = 0.f, d2 = 0.f, d3 = 0.f;
  for (; j + 4 <= en; j += 4) {
    int s0 = srcp[j], s1 = srcp[j + 1], s2 = srcp[j + 2], s3 = srcp[j + 3];
    d0 += nmask[s0]; d1 += nmask[s1]; d2 += nmask[s2]; d3 += nmask[s3];
  }
  for (; j < en; ++j) d0 += nmask[srcp[j]];
  d += d0 + d1 + d2 + d3;
  float di = (nm > 0.f) ? (1.0f / sqrtf(d)) : 0.f;
  dinv[i] = di;
  selfw[i] = di * di * nm;
}

__global__ void k_coef(const int* __restrict__ srcp, const int* __restrict__ dstp,
                       const float* __restrict__ dinv, float* __restrict__ coefp) {
  int j = blockIdx.x * 256 + threadIdx.x;
  if (j < E_) coefp[j] = dinv[srcp[j]] * dinv[dstp[j]];
}

// ---- feature aggregation + bias + relu + fused score matvec ---------------
__global__ __launch_bounds__(256) void k_agg(const float4* __restrict__ t4,
                                             const float* __restrict__ coefp,
                                             const int* __restrict__ off,
                                             const int* __restrict__ srcp,
                                             const float* __restrict__ selfw,
                                             const float* __restrict__ bias,
                                             const float* __restrict__ Wp,
                                             float4* __restrict__ h4,
                                             float* __restrict__ t1) {
  const int node = blockIdx.x * 8 + (threadIdx.x >> 5);
  const int lane = threadIdx.x & 31;
  float sw = selfw[node];
  float4 self = t4[(size_t)node * 32 + lane];
  float4 acc = make_float4(sw * self.x, sw * self.y, sw * self.z, sw * self.w);
  int s = off[node], en = off[node + 1];
  int j = s;
  for (; j + 4 <= en; j += 4) {
    int s0 = srcp[j], s1 = srcp[j + 1], s2 = srcp[j + 2], s3 = srcp[j + 3];
    float c0 = coefp[j], c1 = coefp[j + 1], c2 = coefp[j + 2], c3 = coefp[j + 3];
    float4 r0 = t4[(size_t)s0 * 32 + lane];
    float4 r1 = t4[(size_t)s1 * 32 + lane];
    float4 r2 = t4[(size_t)s2 * 32 + lane];
    float4 r3 = t4[(size_t)s3 * 32 + lane];
    acc.x += c0 * r0.x + c1 * r1.x + c2 * r2.x + c3 * r3.x;
    acc.y += c0 * r0.y + c1 * r1.y + c2 * r2.y + c3 * r3.y;
    acc.z += c0 * r0.z + c1 * r1.z + c2 * r2.z + c3 * r3.z;
    acc.w += c0 * r0.w + c1 * r1.w + c2 * r2.w + c3 * r3.w;
  }
  for (; j < en; ++j) {
    int s0 = srcp[j];
    float c0 = coefp[j];
    float4 r0 = t4[(size_t)s0 * 32 + lane];
    acc.x += c0 * r0.x; acc.y += c0 * r0.y; acc.z += c0 * r0.z; acc.w += c0 * r0.w;
  }
  float4 b4 = ((const float4*)bias)[lane];
  acc.x = fmaxf(acc.x + b4.x, 0.f);
  acc.y = fmaxf(acc.y + b4.y, 0.f);
  acc.z = fmaxf(acc.z + b4.z, 0.f);
  acc.w = fmaxf(acc.w + b4.w, 0.f);
  h4[(size_t)node * 32 + lane] = acc;
  float4 wp = ((const float4*)Wp)[lane];
  float part = acc.x * wp.x + acc.y * wp.y + acc.z * wp.z + acc.w * wp.w;
#pragma unroll
  for (int o = 16; o > 0; o >>= 1) part += __shfl_down(part, o, 32);
  if (lane == 0) t1[node] = part;
}

// ---- score aggregation ----------------------------------------------------
__global__ void k_sagg(const float* __restrict__ t1, const float* __restrict__ coefp,
                       const int* __restrict__ off, const int* __restrict__ srcp,
                       const float* __restrict__ selfw,
                       const float* __restrict__ bp, float* __restrict__ score) {
  int i = blockIdx.x * 256 + threadIdx.x;
  if (i >= NT) return;
  float a0 = selfw[i] * t1[i], a1 = 0.f, a2 = 0.f, a3 = 0.f;
  int s = off[i], en = off[i + 1];
  int j = s;
  for (; j + 4 <= en; j += 4) {
    int s0 = srcp[j], s1 = srcp[j + 1], s2 = srcp[j + 2], s3 = srcp[j + 3];
    float c0 = coefp[j], c1 = coefp[j + 1], c2 = coefp[j + 2], c3 = coefp[j + 3];
    a0 += c0 * t1[s0]; a1 += c1 * t1[s1]; a2 += c2 * t1[s2]; a3 += c3 * t1[s3];
  }
  for (; j < en; ++j) a0 += coefp[j] * t1[srcp[j]];
  score[i] = a0 + a1 + a2 + a3 + bp[0];
}

// ---- per-graph top-k ------------------------------------------------------
__global__ __launch_bounds__(1024) void k_topk(const float* __restrict__ score,
                                               float* __restrict__ nmask,
                                               float* __restrict__ scale, int k) {
  __shared__ float s[2048];
  __shared__ unsigned int ebits[64];
  __shared__ float Tsh;
  __shared__ int cgt_sh;
  const int g = blockIdx.x, t = threadIdx.x;
  const int n0 = g * N_ + t, n1 = n0 + 1024;
  float raw0 = score[n0], raw1 = score[n1];
  float ms0 = (nmask[n0] > 0.f) ? raw0 : -INFINITY;
  float ms1 = (nmask[n1] > 0.f) ? raw1 : -INFINITY;
  s[t] = ms0;
  s[t + 1024] = ms1;
  if (t < 64) ebits[t] = 0u;
  __syncthreads();
  for (int size = 2; size <= 2048; size <<= 1) {
    for (int stride = size >> 1; stride > 0; stride >>= 1) {
#pragma unroll
      for (int q = 0; q < 2; ++q) {
        int i = t + q * 1024;
        int j = i ^ stride;
        if (j > i) {
          float a = s[i], b = s[j];
          bool lowSeg = (i & size) == 0;
          if ((lowSeg && a < b) || (!lowSeg && a > b)) { s[i] = b; s[j] = a; }
        }
      }
      __syncthreads();
    }
  }
  if (t == 0) {
    float T = s[k - 1];
    Tsh = T;
    int lo = 0, hi = 2048;
    while (lo < hi) {
      int mid = (lo + hi) >> 1;
      if (s[mid] > T) lo = mid + 1; else hi = mid;
    }
    cgt_sh = lo;
  }
  __syncthreads();
  const float T = Tsh;
  const int need = k - cgt_sh;
  if (ms0 == T) atomicOr(&ebits[t >> 5], 1u << (t & 31));
  if (ms1 == T) atomicOr(&ebits[(t + 1024) >> 5], 1u << (t & 31));
  __syncthreads();
  float kp0 = (ms0 > T) ? 1.f : 0.f;
  if (ms0 == T) {
    int w = t >> 5;
    int rank = __popc(ebits[w] & ((1u << (t & 31)) - 1u));
    for (int u = 0; u < w; ++u) rank += __popc(ebits[u]);
    kp0 = (rank < need) ? 1.f : 0.f;
  }
  float kp1 = (ms1 > T) ? 1.f : 0.f;
  if (ms1 == T) {
    int n = t + 1024, w = n >> 5;
    int rank = __popc(ebits[w] & ((1u << (n & 31)) - 1u));
    for (int u = 0; u < w; ++u) rank += __popc(ebits[u]);
    kp1 = (rank < need) ? 1.f : 0.f;
  }
  nmask[n0] = kp0;
  nmask[n1] = kp1;
  scale[n0] = kp0 * tanhf(raw0);
  scale[n1] = kp1 * tanhf(raw1);
}

// ---- readout stage 1: per-(graph, 64-node part) partial [max, sum] --------
// grid (B, RPARTS) x 256 thr; 32 lanes (float4 feats) x 8 node-groups x 8 it.
__global__ __launch_bounds__(256) void k_readout1(const float4* __restrict__ h4,
                                                  const float* __restrict__ scale,
                                                  const float* __restrict__ nmask,
                                                  float4* __restrict__ pmx,
                                                  float4* __restrict__ psm) {
  __shared__ float4 smx[256], ssm[256];
  const int g = blockIdx.x, part = blockIdx.y;
  const int lane = threadIdx.x & 31;
  const int ng = threadIdx.x >> 5;
  const int nbase = g * N_ + part * (N_ / RPARTS);
  float4 mx = make_float4(-INFINITY, -INFINITY, -INFINITY, -INFINITY);
  float4 sm = make_float4(0.f, 0.f, 0.f, 0.f);
#pragma unroll
  for (int it = 0; it < (N_ / RPARTS) / 8; ++it) {
    int node = nbase + it * 8 + ng;
    float m = nmask[node];
    if (m > 0.f) {
      float sc = scale[node];
      float4 v = h4[(size_t)node * 32 + lane];
      v.x *= sc; v.y *= sc; v.z *= sc; v.w *= sc;
      mx.x = fmaxf(mx.x, v.x); mx.y = fmaxf(mx.y, v.y);
      mx.z = fmaxf(mx.z, v.z); mx.w = fmaxf(mx.w, v.w);
      sm.x += v.x; sm.y += v.y; sm.z += v.z; sm.w += v.w;
    }
  }
  smx[threadIdx.x] = mx;
  ssm[threadIdx.x] = sm;
  __syncthreads();
#pragma unroll
  for (int d = 4; d >= 1; d >>= 1) {
    if (ng < d) {
      float4 omx = smx[threadIdx.x + d * 32];
      float4 osm = ssm[threadIdx.x + d * 32];
      mx.x = fmaxf(mx.x, omx.x); mx.y = fmaxf(mx.y, omx.y);
      mx.z = fmaxf(mx.z, omx.z); mx.w = fmaxf(mx.w, omx.w);
      sm.x += osm.x; sm.y += osm.y; sm.z += osm.z; sm.w += osm.w;
      smx[threadIdx.x] = mx;
      ssm[threadIdx.x] = sm;
    }
    __syncthreads();
  }
  if (ng == 0) {
    pmx[(size_t)(g * RPARTS + part) * 32 + lane] = mx;
    psm[(size_t)(g * RPARTS + part) * 32 + lane] = sm;
  }
}

// ---- readout stage 2: combine parts, accumulate into gacc -----------------
__global__ void k_readout2(const float4* __restrict__ pmx, const float4* __restrict__ psm,
                           float4* __restrict__ gacc, float invk) {
  int g = blockIdx.x, lane = threadIdx.x & 31;  // 32 threads = one float4 row
  float4 mx = make_float4(-INFINITY, -INFINITY, -INFINITY, -INFINITY);
  float4 sm = make_float4(0.f, 0.f, 0.f, 0.f);
  for (int p = 0; p < RPARTS; ++p) {
    float4 omx = pmx[(size_t)(g * RPARTS + p) * 32 + lane];
    float4 osm = psm[(size_t)(g * RPARTS + p) * 32 + lane];
    mx.x = fmaxf(mx.x, omx.x); mx.y = fmaxf(mx.y, omx.y);
    mx.z = fmaxf(mx.z, omx.z); mx.w = fmaxf(mx.w, omx.w);
    sm.x += osm.x; sm.y += osm.y; sm.z += osm.z; sm.w += osm.w;
  }
  float4 a = gacc[(size_t)g * 64 + lane];
  a.x += mx.x; a.y += mx.y; a.z += mx.z; a.w += mx.w;
  gacc[(size_t)g * 64 + lane] = a;
  float4 b = gacc[(size_t)g * 64 + 32 + lane];
  b.x += sm.x * invk; b.y += sm.y * invk; b.z += sm.z * invk; b.w += sm.w * invk;
  gacc[(size_t)g * 64 + 32 + lane] = b;
}

// ---- MLP head + log_softmax ------------------------------------------------
__global__ __launch_bounds__(128) void k_mlp(const float* __restrict__ gacc,
                                             const float* __restrict__ W1,
                                             const float* __restrict__ b1,
                                             const float* __restrict__ W2,
                                             const float* __restrict__ b2,
                                             const float* __restrict__ W3,
                                             const float* __restrict__ b3,
                                             float* __restrict__ out) {
  __shared__ float gr[256], o1[128], o2[64], o3[NCLS];
  int g = blockIdx.x, t = threadIdx.x;
  gr[t] = gacc[g * 256 + t];
  gr[t + 128] = gacc[g * 256 + 128 + t];
  __syncthreads();
  float a = b1[t];
  for (int kk = 0; kk < 256; ++kk) a += gr[kk] * W1[kk * 128 + t];
  o1[t] = fmaxf(a, 0.f);
  __syncthreads();
  if (t < 64) {
    float a2 = b2[t];
    for (int kk = 0; kk < 128; ++kk) a2 += o1[kk] * W2[kk * 64 + t];
    o2[t] = fmaxf(a2, 0.f);
  }
  __syncthreads();
  if (t < NCLS) {
    float a3 = b3[t];
    for (int kk = 0; kk < 64; ++kk) a3 += o2[kk] * W3[kk * NCLS + t];
    o3[t] = a3;
  }
  __syncthreads();
  if (t == 0) {
    float m = -INFINITY;
    for (int c = 0; c < NCLS; ++c) m = fmaxf(m, o3[c]);
    float sum = 0.f;
    for (int c = 0; c < NCLS; ++c) sum += expf(o3[c] - m);
    float lse = logf(sum);
    for (int c = 0; c < NCLS; ++c) out[g * NCLS + c] = o3[c] - m - lse;
  }
}

}  // namespace

extern "C" void kernel_launch(void* const* d_in, const int* in_sizes, int n_in,
                              void* d_out, int out_size, void* d_ws, size_t ws_size,
                              hipStream_t stream) {
  const float* x = (const float*)d_in[0];
  const int* ei = (const int*)d_in[1];
  const int* src = ei;
  const int* dst = ei + E_;
  const float* Wl[3]  = {(const float*)d_in[3], (const float*)d_in[7], (const float*)d_in[11]};
  const float* bl[3]  = {(const float*)d_in[4], (const float*)d_in[8], (const float*)d_in[12]};
  const float* Wpl[3] = {(const float*)d_in[5], (const float*)d_in[9], (const float*)d_in[13]};
  const float* bpl[3] = {(const float*)d_in[6], (const float*)d_in[10], (const float*)d_in[14]};
  const float* l1W = (const float*)d_in[15];
  const float* l1b = (const float*)d_in[16];
  const float* l2W = (const float*)d_in[17];
  const float* l2b = (const float*)d_in[18];
  const float* l3W = (const float*)d_in[19];
  const float* l3b = (const float*)d_in[20];

  char* p = (char*)d_ws;
  auto alloc = [&](size_t bytes) -> void* {
    void* r = (void*)p;
    p += (bytes + 255) & ~size_t(255);
    return r;
  };
  float* h      = (float*)alloc((size_t)NT * 128 * 4);
  float* t      = (float*)alloc((size_t)NT * 128 * 4);
  float* dinv   = (float*)alloc(NT * 4);
  float* selfw  = (float*)alloc(NT * 4);
  float* t1     = (float*)alloc(NT * 4);
  float* score  = (float*)alloc(NT * 4);
  float* scale  = (float*)alloc(NT * 4);
  float* nmask  = (float*)alloc(NT * 4);
  float* coefp  = (float*)alloc(E_ * 4);
  int*   srcp   = (int*)alloc(E_ * 4);
  int*   dstp   = (int*)alloc(E_ * 4);
  int*   off    = (int*)alloc((NT + 1) * 4);
  int*   cnt    = (int*)alloc(NT * 4);
  int*   cursor = (int*)alloc(NT * 4);
  int*   eid    = (int*)alloc(E_ * 4);
  int*   bsum   = (int*)alloc(256 * 4);
  float* pmx    = (float*)alloc((size_t)B_ * RPARTS * 128 * 4);
  float* psm    = (float*)alloc((size_t)B_ * RPARTS * 128 * 4);
  float* gacc   = (float*)alloc(B_ * 256 * 4);

  const int K[3] = {1024, 512, 256};

  hipMemsetAsync(cnt, 0, NT * 4, stream);
  hipMemsetAsync(gacc, 0, B_ * 256 * 4, stream);
  k_fill<<<NT / 256, 256, 0, stream>>>(nmask, 1.f, NT);
  k_fill<<<NT / 256, 256, 0, stream>>>(scale, 1.f, NT);

  k_count<<<E_ / 256, 256, 0, stream>>>(dst, cnt);
  k_scan1<<<256, 256, 0, stream>>>(cnt, off, bsum);
  k_scan2<<<1, 256, 0, stream>>>(bsum);
  k_scan3<<<256, 256, 0, stream>>>(off, bsum, cursor);
  k_fill_eid<<<E_ / 256, 256, 0, stream>>>(dst, cursor, eid);
  k_permute<<<E_ / 256, 256, 0, stream>>>(eid, src, dst, srcp, dstp);

  const float* inF = x;
  for (int l = 0; l < 3; ++l) {
    k_matmul<<<NT / 64, 256, 0, stream>>>(inF, scale, Wl[l], t);
    k_deg<<<NT / 256, 256, 0, stream>>>(off, srcp, nmask, dinv, selfw);
    k_coef<<<E_ / 256, 256, 0, stream>>>(srcp, dstp, dinv, coefp);
    k_agg<<<NT / 8, 256, 0, stream>>>((const float4*)t, coefp, off, srcp, selfw,
                                      bl[l], Wpl[l], (float4*)h, t1);
    k_sagg<<<NT / 256, 256, 0, stream>>>(t1, coefp, off, srcp, selfw, bpl[l], score);
    k_topk<<<B_, 1024, 0, stream>>>(score, nmask, scale, K[l]);
    k_readout1<<<dim3(B_, RPARTS), 256, 0, stream>>>((const float4*)h, scale, nmask,
                                                     (float4*)pmx, (float4*)psm);
    k_readout2<<<B_, 32, 0, stream>>>((const float4*)pmx, (const float4*)psm,
                                      (float4*)gacc, 1.f / (float)K[l]);
    inF = h;
  }
  k_mlp<<<B_, 128, 0, stream>>>(gacc, l1W, l1b, l2W, l2b, l3W, l3b, (float*)d_out);
}

// Round 4
// 384.781 us; speedup vs baseline: 2.6634x; 1.3183x over previous
//
#include <hip/hip_runtime.h>
#include <math.h>

// ---------------------------------------------------------------------------
// SAGPool GNN forward: 3x [GCNConv -> SAGPool(top-k) -> readout] + MLP head.
// B=32 graphs x N=2048 nodes; E=524288; 128 feats; K = 1024/512/256.
// R4 changes vs R3 (507us; all kernels <41us; many latency-bound little ones):
//   - k_pool (block=graph) fuses: score aggregation (t1/dinv staged in LDS),
//     radix-select top-k threshold (4x8bit rounds, replaces 66-pass bitonic),
//     index-ordered tie-break, scale=keep*tanh(score), NEXT-layer deg/dinv/
//     selfw from LDS nmask, and a compacted kept-node list (block scan).
//     Replaces k_sagg + k_topk + k_deg + k_coef per layer.
//   - layers 2/3: matmul/agg/readout iterate kept lists only (1024/512 rows).
//   - coef computed on the fly in k_agg (dinv[src]*dinv[dst], L2-hot).
//   - CSR: srcp written directly by fill pass; XCD swizzle in k_agg.
// ---------------------------------------------------------------------------

namespace {

constexpr int B_  = 32;
constexpr int N_  = 2048;
constexpr int NT  = B_ * N_;        // 65536
constexpr int E_  = B_ * 16384;     // 524288
constexpr int NCLS = 10;
constexpr int RPARTS = 32;

__global__ void k_fill(float* __restrict__ p, float v, int n) {
  int i = blockIdx.x * blockDim.x + threadIdx.x;
  if (i < n) p[i] = v;
}

// ---- CSR build -------------------------------------------------------------
__global__ void k_count(const int* __restrict__ dst, int* __restrict__ cnt) {
  int e = blockIdx.x * 256 + threadIdx.x;
  if (e < E_) atomicAdd(&cnt[dst[e]], 1);
}

__global__ void k_scan1(const int* __restrict__ cnt, int* __restrict__ off,
                        int* __restrict__ bsum) {
  __shared__ int s[256];
  int t = threadIdx.x;
  int i = blockIdx.x * 256 + t;
  int v = cnt[i];
  s[t] = v;
  __syncthreads();
  for (int d = 1; d < 256; d <<= 1) {
    int add = (t >= d) ? s[t - d] : 0;
    __syncthreads();
    s[t] += add;
    __syncthreads();
  }
  off[i] = s[t] - v;
  if (t == 255) bsum[blockIdx.x] = s[255];
}

__global__ void k_scan2(int* __restrict__ bsum) {
  __shared__ int s[256];
  int t = threadIdx.x;
  int v = bsum[t];
  s[t] = v;
  __syncthreads();
  for (int d = 1; d < 256; d <<= 1) {
    int add = (t >= d) ? s[t - d] : 0;
    __syncthreads();
    s[t] += add;
    __syncthreads();
  }
  bsum[t] = s[t] - v;
}

__global__ void k_scan3(int* __restrict__ off, const int* __restrict__ bsum,
                        int* __restrict__ cursor) {
  int i = blockIdx.x * 256 + threadIdx.x;
  int v = off[i] + bsum[blockIdx.x];
  off[i] = v;
  cursor[i] = v;
  if (i == NT - 1) off[NT] = E_;
}

// writes srcp directly in CSR slot order (no eid indirection kept)
__global__ void k_fill_srcp(const int* __restrict__ src, const int* __restrict__ dst,
                            int* __restrict__ cursor, int* __restrict__ srcp) {
  int e = blockIdx.x * 256 + threadIdx.x;
  if (e < E_) {
    int p = atomicAdd(&cursor[dst[e]], 1);
    srcp[p] = src[e];
  }
}

// layer-0 deg: all masks are 1 -> deg = 1 + indegree (pure CSR counts)
__global__ void k_deg0(const int* __restrict__ off, float* __restrict__ dinv,
                       float* __restrict__ selfw) {
  int i = blockIdx.x * 256 + threadIdx.x;
  if (i >= NT) return;
  float d = 1.f + (float)(off[i + 1] - off[i]);
  float di = 1.f / sqrtf(d);
  dinv[i] = di;
  selfw[i] = di * di;
}

// ---- dense matmul: C[rows x 128] = (scale .* A)[rows x 128] @ W ------------
// kept!=null: logical row q -> global row kept[(q>>kshift)*N_ + (q & (K-1))]
__global__ __launch_bounds__(256) void k_matmul(const float* __restrict__ A,
                                                const float* __restrict__ scale,
                                                const float* __restrict__ W,
                                                float* __restrict__ C,
                                                const int* __restrict__ kept,
                                                int kshift) {
  __shared__ float Ast[32][68];
  __shared__ float Ws[32][128];
  __shared__ int rowid[64];
  __shared__ float rsc[64];
  const int tid = threadIdx.x;
  if (tid < 64) {
    int q = blockIdx.x * 64 + tid;
    int row;
    if (kept) {
      int g = q >> kshift;
      row = kept[g * N_ + (q - (g << kshift))];
    } else {
      row = q;
    }
    rowid[tid] = row;
    rsc[tid] = scale[row];
  }
  __syncthreads();
  const int rowq = tid >> 4;
  const int colq = tid & 15;
  float acc[4][8] = {};
  for (int k0 = 0; k0 < 128; k0 += 32) {
    {
      int kk = tid & 31, rr = tid >> 5;
#pragma unroll
      for (int it = 0; it < 8; ++it) {
        int r = rr + 8 * it;
        Ast[kk][r] = A[(size_t)rowid[r] * 128 + k0 + kk] * rsc[r];
      }
    }
    {
      const float4* W4 = (const float4*)W;
      float4* Ws4 = (float4*)Ws;
#pragma unroll
      for (int it = 0; it < 4; ++it)
        Ws4[tid + 256 * it] = W4[k0 * 32 + tid + 256 * it];
    }
    __syncthreads();
#pragma unroll
    for (int kk = 0; kk < 32; ++kk) {
      float4 av = *(const float4*)&Ast[kk][4 * rowq];
      const float4* wrow = (const float4*)&Ws[kk][0];
      float4 w0 = wrow[2 * colq], w1 = wrow[2 * colq + 1];
      float a[4] = {av.x, av.y, av.z, av.w};
      float w[8] = {w0.x, w0.y, w0.z, w0.w, w1.x, w1.y, w1.z, w1.w};
#pragma unroll
      for (int r = 0; r < 4; ++r)
#pragma unroll
        for (int j = 0; j < 8; ++j) acc[r][j] += a[r] * w[j];
    }
    __syncthreads();
  }
#pragma unroll
  for (int r = 0; r < 4; ++r) {
    float4* Crow = (float4*)&C[(size_t)rowid[4 * rowq + r] * 128 + 8 * colq];
    Crow[0] = make_float4(acc[r][0], acc[r][1], acc[r][2], acc[r][3]);
    Crow[1] = make_float4(acc[r][4], acc[r][5], acc[r][6], acc[r][7]);
  }
}

// ---- feature aggregation + bias + relu + fused score matvec ---------------
// coef on the fly: dinv[src]*dinv[dst]. XCD swizzle on block index.
__global__ __launch_bounds__(256) void k_agg(const float4* __restrict__ t4,
                                             const int* __restrict__ off,
                                             const int* __restrict__ srcp,
                                             const float* __restrict__ dinv,
                                             const float* __restrict__ selfw,
                                             const float* __restrict__ bias,
                                             const float* __restrict__ Wp,
                                             float4* __restrict__ h4,
                                             float* __restrict__ t1,
                                             const int* __restrict__ kept,
                                             int kshift) {
  int chunk = gridDim.x >> 3;
  int bs = ((blockIdx.x & 7) * chunk) + (blockIdx.x >> 3);  // XCD L2 locality
  int q = bs * 8 + (threadIdx.x >> 5);
  int node;
  if (kept) {
    int g = q >> kshift;
    node = kept[g * N_ + (q - (g << kshift))];
  } else {
    node = q;
  }
  const int lane = threadIdx.x & 31;
  const float dvi = dinv[node];
  float sw = selfw[node];
  float4 self = t4[(size_t)node * 32 + lane];
  float4 acc = make_float4(sw * self.x, sw * self.y, sw * self.z, sw * self.w);
  int s = off[node], en = off[node + 1];
  int j = s;
  for (; j + 4 <= en; j += 4) {
    int s0 = srcp[j], s1 = srcp[j + 1], s2 = srcp[j + 2], s3 = srcp[j + 3];
    float c0 = dinv[s0] * dvi, c1 = dinv[s1] * dvi;
    float c2 = dinv[s2] * dvi, c3 = dinv[s3] * dvi;
    float4 r0 = t4[(size_t)s0 * 32 + lane];
    float4 r1 = t4[(size_t)s1 * 32 + lane];
    float4 r2 = t4[(size_t)s2 * 32 + lane];
    float4 r3 = t4[(size_t)s3 * 32 + lane];
    acc.x += c0 * r0.x + c1 * r1.x + c2 * r2.x + c3 * r3.x;
    acc.y += c0 * r0.y + c1 * r1.y + c2 * r2.y + c3 * r3.y;
    acc.z += c0 * r0.z + c1 * r1.z + c2 * r2.z + c3 * r3.z;
    acc.w += c0 * r0.w + c1 * r1.w + c2 * r2.w + c3 * r3.w;
  }
  for (; j < en; ++j) {
    int s0 = srcp[j];
    float c0 = dinv[s0] * dvi;
    float4 r0 = t4[(size_t)s0 * 32 + lane];
    acc.x += c0 * r0.x; acc.y += c0 * r0.y; acc.z += c0 * r0.z; acc.w += c0 * r0.w;
  }
  float4 b4 = ((const float4*)bias)[lane];
  acc.x = fmaxf(acc.x + b4.x, 0.f);
  acc.y = fmaxf(acc.y + b4.y, 0.f);
  acc.z = fmaxf(acc.z + b4.z, 0.f);
  acc.w = fmaxf(acc.w + b4.w, 0.f);
  h4[(size_t)node * 32 + lane] = acc;
  float4 wp = ((const float4*)Wp)[lane];
  float part = acc.x * wp.x + acc.y * wp.y + acc.z * wp.z + acc.w * wp.w;
#pragma unroll
  for (int o = 16; o > 0; o >>= 1) part += __shfl_down(part, o, 32);
  if (lane == 0) t1[node] = part;
}

// ---- fused pool: score agg + radix top-k + scale + next-layer deg + kept --
// one block per graph, 1024 threads; thread t owns nodes t and t+1024.
__global__ __launch_bounds__(1024) void k_pool(const float* __restrict__ t1,
                                               const int* __restrict__ off,
                                               const int* __restrict__ srcp,
                                               float* __restrict__ dinv,
                                               float* __restrict__ selfw,
                                               const float* __restrict__ bp,
                                               float* __restrict__ scale,
                                               int* __restrict__ kept, int k) {
  __shared__ float st1[2048];
  __shared__ float sdv[2048];
  __shared__ unsigned skey[2048];
  __shared__ float skp[2048];
  __shared__ unsigned hist[256];
  __shared__ unsigned ebits[64];
  __shared__ int wsum[16];
  __shared__ unsigned bc_digit, bc_prev;
  const int g = blockIdx.x, t = threadIdx.x;
  const int base = g * N_;
  st1[t] = t1[base + t];
  st1[t + 1024] = t1[base + t + 1024];
  sdv[t] = dinv[base + t];
  sdv[t + 1024] = dinv[base + t + 1024];
  float sw[2] = {selfw[base + t], selfw[base + t + 1024]};
  if (t < 64) ebits[t] = 0u;
  if (t < 256) hist[t] = 0u;
  __syncthreads();
  // score for my two nodes (score agg in LDS; coef = dinv_s * dinv_d)
  float raw[2];
  unsigned key[2];
  float bpv = bp[0];
#pragma unroll
  for (int q = 0; q < 2; ++q) {
    int n = t + q * 1024;
    float di = sdv[n];
    float a = 0.f;
    int s = off[base + n], en = off[base + n + 1];
    for (int j = s; j < en; ++j) {
      int sl = srcp[j] - base;
      a += sdv[sl] * st1[sl];
    }
    raw[q] = sw[q] * st1[n] + di * a + bpv;
    // descending sortable key; dead (di==0) -> max key
    unsigned u = __float_as_uint(raw[q]);
    u = (u & 0x80000000u) ? ~u : (u | 0x80000000u);  // ascending float order
    u = ~u;                                          // descending
    if (di <= 0.f) u = 0xFFFFFFFFu;
    key[q] = u;
    skey[n] = u;
  }
  __syncthreads();
  // radix-select k-th smallest key (== k-th largest score), 4 x 8-bit rounds
  unsigned prefix = 0u, rem = (unsigned)k;
  for (int shift = 24; shift >= 0; shift -= 8) {
    unsigned mask = (shift == 24) ? 0u : (0xFFFFFFFFu << (shift + 8));
#pragma unroll
    for (int q = 0; q < 2; ++q)
      if ((key[q] & mask) == prefix) atomicAdd(&hist[(key[q] >> shift) & 255u], 1u);
    __syncthreads();
    for (int o = 1; o < 256; o <<= 1) {  // inclusive scan of hist
      unsigned v = 0u;
      if (t < 256 && t >= o) v = hist[t - o];
      __syncthreads();
      if (t < 256) hist[t] += v;
      __syncthreads();
    }
    if (t < 256) {
      unsigned inc = hist[t], exc = t ? hist[t - 1] : 0u;
      if (inc >= rem && exc < rem) { bc_digit = (unsigned)t; bc_prev = exc; }
    }
    __syncthreads();
    prefix |= bc_digit << shift;
    rem -= bc_prev;
    if (t < 256) hist[t] = 0u;
    __syncthreads();
  }
  const unsigned Tkey = prefix;
  const int need = (int)rem;  // ties to keep, lowest index first
#pragma unroll
  for (int q = 0; q < 2; ++q) {
    int n = t + q * 1024;
    if (key[q] == Tkey) atomicOr(&ebits[n >> 5], 1u << (n & 31));
  }
  __syncthreads();
#pragma unroll
  for (int q = 0; q < 2; ++q) {
    int n = t + q * 1024;
    float kp;
    if (key[q] < Tkey) {
      kp = 1.f;
    } else if (key[q] == Tkey) {
      int w = n >> 5;
      int rank = __popc(ebits[w] & ((1u << (n & 31)) - 1u));
      for (int u = 0; u < w; ++u) rank += __popc(ebits[u]);
      kp = (rank < need) ? 1.f : 0.f;
    } else {
      kp = 0.f;
    }
    skp[n] = kp;
    scale[base + n] = kp * tanhf(raw[q]);
  }
  __syncthreads();
  // compacted kept list (ascending node index): pair-wise block scan
  {
    int lane = t & 63, w = t >> 6;
    int a0 = (int)skp[2 * t], a1 = (int)skp[2 * t + 1];
    int ps = a0 + a1;
    int v = ps;
#pragma unroll
    for (int o = 1; o < 64; o <<= 1) {
      int nv = __shfl_up(v, o);
      if (lane >= o) v += nv;
    }
    if (lane == 63) wsum[w] = v;
    __syncthreads();
    if (t == 0) {
      int accv = 0;
      for (int i = 0; i < 16; ++i) { int tmp = wsum[i]; wsum[i] = accv; accv += tmp; }
    }
    __syncthreads();
    int excl = wsum[w] + v - ps;
    if (a0) kept[base + excl] = base + 2 * t;
    if (a1) kept[base + excl + a0] = base + 2 * t + 1;
  }
  // next-layer deg/dinv/selfw from new nmask (in LDS)
#pragma unroll
  for (int q = 0; q < 2; ++q) {
    int n = t + q * 1024;
    float nm = skp[n];
    float d = nm;
    int s = off[base + n], en = off[base + n + 1];
    for (int j = s; j < en; ++j) d += skp[srcp[j] - base];
    float di = (nm > 0.f) ? (1.f / sqrtf(d)) : 0.f;
    dinv[base + n] = di;
    selfw[base + n] = di * di * nm;
  }
}

// ---- readout stage 1 over kept list: per-(graph,part) partial [max,sum] ---
__global__ __launch_bounds__(256) void k_readout1(const float4* __restrict__ h4,
                                                  const float* __restrict__ scale,
                                                  const int* __restrict__ kept,
                                                  int perpart, int npg,
                                                  float4* __restrict__ pmx,
                                                  float4* __restrict__ psm) {
  __shared__ float4 smx[256], ssm[256];
  const int g = blockIdx.x, part = blockIdx.y;
  const int lane = threadIdx.x & 31;
  const int ng = threadIdx.x >> 5;
  float4 mx = make_float4(-INFINITY, -INFINITY, -INFINITY, -INFINITY);
  float4 sm = make_float4(0.f, 0.f, 0.f, 0.f);
  for (int it = 0; it < npg; ++it) {
    int node = kept[g * N_ + part * perpart + it * 8 + ng];
    float sc = scale[node];
    float4 v = h4[(size_t)node * 32 + lane];
    v.x *= sc; v.y *= sc; v.z *= sc; v.w *= sc;
    mx.x = fmaxf(mx.x, v.x); mx.y = fmaxf(mx.y, v.y);
    mx.z = fmaxf(mx.z, v.z); mx.w = fmaxf(mx.w, v.w);
    sm.x += v.x; sm.y += v.y; sm.z += v.z; sm.w += v.w;
  }
  smx[threadIdx.x] = mx;
  ssm[threadIdx.x] = sm;
  __syncthreads();
#pragma unroll
  for (int d = 4; d >= 1; d >>= 1) {
    if (ng < d) {
      float4 omx = smx[threadIdx.x + d * 32];
      float4 osm = ssm[threadIdx.x + d * 32];
      mx.x = fmaxf(mx.x, omx.x); mx.y = fmaxf(mx.y, omx.y);
      mx.z = fmaxf(mx.z, omx.z); mx.w = fmaxf(mx.w, omx.w);
      sm.x += osm.x; sm.y += osm.y; sm.z += osm.z; sm.w += osm.w;
      smx[threadIdx.x] = mx;
      ssm[threadIdx.x] = sm;
    }
    __syncthreads();
  }
  if (ng == 0) {
    pmx[(size_t)(g * RPARTS + part) * 32 + lane] = mx;
    psm[(size_t)(g * RPARTS + part) * 32 + lane] = sm;
  }
}

__global__ void k_readout2(const float4* __restrict__ pmx, const float4* __restrict__ psm,
                           float4* __restrict__ gacc, float invk) {
  int g = blockIdx.x, lane = threadIdx.x & 31;
  float4 mx = make_float4(-INFINITY, -INFINITY, -INFINITY, -INFINITY);
  float4 sm = make_float4(0.f, 0.f, 0.f, 0.f);
  for (int p = 0; p < RPARTS; ++p) {
    float4 omx = pmx[(size_t)(g * RPARTS + p) * 32 + lane];
    float4 osm = psm[(size_t)(g * RPARTS + p) * 32 + lane];
    mx.x = fmaxf(mx.x, omx.x); mx.y = fmaxf(mx.y, omx.y);
    mx.z = fmaxf(mx.z, omx.z); mx.w = fmaxf(mx.w, omx.w);
    sm.x += osm.x; sm.y += osm.y; sm.z += osm.z; sm.w += osm.w;
  }
  float4 a = gacc[(size_t)g * 64 + lane];
  a.x += mx.x; a.y += mx.y; a.z += mx.z; a.w += mx.w;
  gacc[(size_t)g * 64 + lane] = a;
  float4 b = gacc[(size_t)g * 64 + 32 + lane];
  b.x += sm.x * invk; b.y += sm.y * invk; b.z += sm.z * invk; b.w += sm.w * invk;
  gacc[(size_t)g * 64 + 32 + lane] = b;
}

// ---- MLP head + log_softmax ------------------------------------------------
__global__ __launch_bounds__(128) void k_mlp(const float* __restrict__ gacc,
                                             const float* __restrict__ W1,
                                             const float* __restrict__ b1,
                                             const float* __restrict__ W2,
                                             const float* __restrict__ b2,
                                             const float* __restrict__ W3,
                                             const float* __restrict__ b3,
                                             float* __restrict__ out) {
  __shared__ float gr[256], o1[128], o2[64], o3[NCLS];
  int g = blockIdx.x, t = threadIdx.x;
  gr[t] = gacc[g * 256 + t];
  gr[t + 128] = gacc[g * 256 + 128 + t];
  __syncthreads();
  float a = b1[t];
  for (int kk = 0; kk < 256; ++kk) a += gr[kk] * W1[kk * 128 + t];
  o1[t] = fmaxf(a, 0.f);
  __syncthreads();
  if (t < 64) {
    float a2 = b2[t];
    for (int kk = 0; kk < 128; ++kk) a2 += o1[kk] * W2[kk * 64 + t];
    o2[t] = fmaxf(a2, 0.f);
  }
  __syncthreads();
  if (t < NCLS) {
    float a3 = b3[t];
    for (int kk = 0; kk < 64; ++kk) a3 += o2[kk] * W3[kk * NCLS + t];
    o3[t] = a3;
  }
  __syncthreads();
  if (t == 0) {
    float m = -INFINITY;
    for (int c = 0; c < NCLS; ++c) m = fmaxf(m, o3[c]);
    float sum = 0.f;
    for (int c = 0; c < NCLS; ++c) sum += expf(o3[c] - m);
    float lse = logf(sum);
    for (int c = 0; c < NCLS; ++c) out[g * NCLS + c] = o3[c] - m - lse;
  }
}

}  // namespace

extern "C" void kernel_launch(void* const* d_in, const int* in_sizes, int n_in,
                              void* d_out, int out_size, void* d_ws, size_t ws_size,
                              hipStream_t stream) {
  const float* x = (const float*)d_in[0];
  const int* ei = (const int*)d_in[1];
  const int* src = ei;
  const int* dst = ei + E_;
  const float* Wl[3]  = {(const float*)d_in[3], (const float*)d_in[7], (const float*)d_in[11]};
  const float* bl[3]  = {(const float*)d_in[4], (const float*)d_in[8], (const float*)d_in[12]};
  const float* Wpl[3] = {(const float*)d_in[5], (const float*)d_in[9], (const float*)d_in[13]};
  const float* bpl[3] = {(const float*)d_in[6], (const float*)d_in[10], (const float*)d_in[14]};
  const float* l1W = (const float*)d_in[15];
  const float* l1b = (const float*)d_in[16];
  const float* l2W = (const float*)d_in[17];
  const float* l2b = (const float*)d_in[18];
  const float* l3W = (const float*)d_in[19];
  const float* l3b = (const float*)d_in[20];

  char* p = (char*)d_ws;
  auto alloc = [&](size_t bytes) -> void* {
    void* r = (void*)p;
    p += (bytes + 255) & ~size_t(255);
    return r;
  };
  float* h      = (float*)alloc((size_t)NT * 128 * 4);
  float* t      = (float*)alloc((size_t)NT * 128 * 4);
  float* dinv   = (float*)alloc(NT * 4);
  float* selfw  = (float*)alloc(NT * 4);
  float* t1     = (float*)alloc(NT * 4);
  float* scale  = (float*)alloc(NT * 4);
  int*   srcp   = (int*)alloc(E_ * 4);
  int*   off    = (int*)alloc((NT + 1) * 4);
  int*   cnt    = (int*)alloc(NT * 4);
  int*   cursor = (int*)alloc(NT * 4);
  int*   bsum   = (int*)alloc(256 * 4);
  int*   kept0  = (int*)alloc(NT * 4);
  int*   kept1  = (int*)alloc(NT * 4);
  int*   kept2  = (int*)alloc(NT * 4);
  float* pmx    = (float*)alloc((size_t)B_ * RPARTS * 128 * 4);
  float* psm    = (float*)alloc((size_t)B_ * RPARTS * 128 * 4);
  float* gacc   = (float*)alloc(B_ * 256 * 4);

  int* keptL[3] = {kept0, kept1, kept2};
  const int K[3] = {1024, 512, 256};
  const int KSH[3] = {10, 9, 8};

  hipMemsetAsync(cnt, 0, NT * 4, stream);
  hipMemsetAsync(gacc, 0, B_ * 256 * 4, stream);
  k_fill<<<NT / 256, 256, 0, stream>>>(scale, 1.f, NT);

  k_count<<<E_ / 256, 256, 0, stream>>>(dst, cnt);
  k_scan1<<<256, 256, 0, stream>>>(cnt, off, bsum);
  k_scan2<<<1, 256, 0, stream>>>(bsum);
  k_scan3<<<256, 256, 0, stream>>>(off, bsum, cursor);
  k_fill_srcp<<<E_ / 256, 256, 0, stream>>>(src, dst, cursor, srcp);
  k_deg0<<<NT / 256, 256, 0, stream>>>(off, dinv, selfw);

  const float* inF = x;
  for (int l = 0; l < 3; ++l) {
    const int* inKept = (l == 0) ? nullptr : keptL[l - 1];
    int inKsh = (l == 0) ? 11 : KSH[l - 1];
    int nrows = (l == 0) ? NT : B_ * K[l - 1];
    k_matmul<<<nrows / 64, 256, 0, stream>>>(inF, scale, Wl[l], t, inKept, inKsh);
    k_agg<<<nrows / 8, 256, 0, stream>>>((const float4*)t, off, srcp, dinv, selfw,
                                         bl[l], Wpl[l], (float4*)h, t1, inKept, inKsh);
    k_pool<<<B_, 1024, 0, stream>>>(t1, off, srcp, dinv, selfw, bpl[l], scale,
                                    keptL[l], K[l]);
    k_readout1<<<dim3(B_, RPARTS), 256, 0, stream>>>((const float4*)h, scale, keptL[l],
                                                     K[l] / RPARTS, K[l] / RPARTS / 8,
                                                     (float4*)pmx, (float4*)psm);
    k_readout2<<<B_, 32, 0, stream>>>((const float4*)pmx, (const float4*)psm,
                                      (float4*)gacc, 1.f / (float)K[l]);
    inF = h;
  }
  k_mlp<<<B_, 128, 0, stream>>>(gacc, l1W, l1b, l2W, l2b, l3W, l3b, (float*)d_out);
}